// Round 1
// baseline (2676.142 us; speedup 1.0000x reference)
//
#include <hip/hip_runtime.h>
#include <hip/hip_bf16.h>
#include <stdint.h>

#define DIM 4096
#define NB 4
#define SEQ 2048

typedef __bf16 bf16_t;
typedef __bf16 bf16x8 __attribute__((ext_vector_type(8)));
typedef float f32x4 __attribute__((ext_vector_type(4)));

__device__ __forceinline__ uint16_t f2bf_u(float f) {
  union { float f; uint32_t u; } v; v.f = f;
  uint32_t r = v.u + 0x7FFFu + ((v.u >> 16) & 1u);
  return (uint16_t)(r >> 16);
}

// ---------------- fp32 -> bf16 conversion (vectorized, grid-stride) ----------------
__global__ __launch_bounds__(256) void cvt_f32_bf16_k(const float* __restrict__ in,
                                                      uint16_t* __restrict__ out, long n) {
  long i = ((long)blockIdx.x * 256 + threadIdx.x) * 8;
  long stride = (long)gridDim.x * 256 * 8;
  for (; i < n; i += stride) {
    float4 a = *(const float4*)(in + i);
    float4 b = *(const float4*)(in + i + 4);
    ushort4 o0 = make_ushort4(f2bf_u(a.x), f2bf_u(a.y), f2bf_u(a.z), f2bf_u(a.w));
    ushort4 o1 = make_ushort4(f2bf_u(b.x), f2bf_u(b.y), f2bf_u(b.z), f2bf_u(b.w));
    *(ushort4*)(out + i) = o0;
    *(ushort4*)(out + i + 4) = o1;
  }
}

// ---------------- async global->LDS helper ----------------
__device__ __forceinline__ void gload16(const void* g, void* l) {
  __builtin_amdgcn_global_load_lds(
      (const __attribute__((address_space(1))) void*)g,
      (__attribute__((address_space(3))) void*)l,
      16, 0, 0);
}

// ---------------- bf16 GEMM: C[m][n] = sum_k A[m][k] * B[n][k] ----------------
// m97-structure: 128x128 tile, BK=32, 4 waves, global_load_lds(16B), 16x16x32 MFMA.
// EPI 0: store bf16   EPI 1: store fp32   EPI 2: store bf16( Xadd + silu(acc) )
template <int EPI>
__global__ __launch_bounds__(256, 2) void gemm_bt(
    const bf16_t* __restrict__ A,  // [M][K]
    const bf16_t* __restrict__ B,  // [N][K]
    void* __restrict__ Cout,
    const float* __restrict__ Xadd,
    int M, int N, int K) {
  __shared__ bf16_t As[128 * 32];
  __shared__ bf16_t Bs[128 * 32];
  const int tid = threadIdx.x;
  const int lane = tid & 63;
  const int wave = tid >> 6;
  const int nbn = N >> 7;
  const int bm = (int)blockIdx.x / nbn;
  const int bn = (int)blockIdx.x % nbn;

  // staging: thread t stages 16B chunks t and t+256 of each 128x32 tile
  const int r0 = tid >> 2;       // row 0..63
  const int c0 = (tid & 3) * 8;  // col in elements
  const bf16_t* Ab = A + (long)bm * 128 * K + (long)r0 * K + c0;
  const bf16_t* Bb = B + (long)bn * 128 * K + (long)r0 * K + c0;
  char* AsB = (char*)As + tid * 16;  // = wave*1024 + lane*16 (wave-uniform base + lane*16)
  char* BsB = (char*)Bs + tid * 16;
  const long rowskip = (long)64 * K;

  const int wr = (wave >> 1) * 64;
  const int wc = (wave & 1) * 64;
  const int lr = lane & 15;
  const int lk = (lane >> 4) * 8;

  f32x4 acc[4][4] = {};

  for (int k0 = 0; k0 < K; k0 += 32) {
    gload16(Ab + k0, AsB);
    gload16(Ab + rowskip + k0, AsB + 4096);
    gload16(Bb + k0, BsB);
    gload16(Bb + rowskip + k0, BsB + 4096);
    __syncthreads();  // compiler drains vmcnt before s_barrier

    bf16x8 fa[4], fb[4];
#pragma unroll
    for (int m = 0; m < 4; ++m)
      fa[m] = *(const bf16x8*)&As[(wr + m * 16 + lr) * 32 + lk];
#pragma unroll
    for (int n = 0; n < 4; ++n)
      fb[n] = *(const bf16x8*)&Bs[(wc + n * 16 + lr) * 32 + lk];
#pragma unroll
    for (int m = 0; m < 4; ++m)
#pragma unroll
      for (int n = 0; n < 4; ++n)
        acc[m][n] = __builtin_amdgcn_mfma_f32_16x16x32_bf16(fa[m], fb[n], acc[m][n], 0, 0, 0);
    __syncthreads();
  }

  // epilogue: D elem j -> row = (lane>>4)*4 + j, col = lane&15
  const int rbase = bm * 128 + wr + (lane >> 4) * 4;
  const int cbase = bn * 128 + wc + (lane & 15);
  if constexpr (EPI == 0) {
    uint16_t* C = (uint16_t*)Cout;
#pragma unroll
    for (int m = 0; m < 4; ++m)
#pragma unroll
      for (int n = 0; n < 4; ++n)
#pragma unroll
        for (int j = 0; j < 4; ++j)
          C[(long)(rbase + m * 16 + j) * N + (cbase + n * 16)] = f2bf_u(acc[m][n][j]);
  } else if constexpr (EPI == 1) {
    float* C = (float*)Cout;
#pragma unroll
    for (int m = 0; m < 4; ++m)
#pragma unroll
      for (int n = 0; n < 4; ++n)
#pragma unroll
        for (int j = 0; j < 4; ++j)
          C[(long)(rbase + m * 16 + j) * N + (cbase + n * 16)] = acc[m][n][j];
  } else {  // EPI == 2
    uint16_t* C = (uint16_t*)Cout;
#pragma unroll
    for (int m = 0; m < 4; ++m)
#pragma unroll
      for (int n = 0; n < 4; ++n)
#pragma unroll
        for (int j = 0; j < 4; ++j) {
          long idx = (long)(rbase + m * 16 + j) * N + (cbase + n * 16);
          float h = acc[m][n][j];
          float sl = h / (1.f + __expf(-h));
          C[idx] = f2bf_u(Xadd[idx] + sl);
        }
  }
}

// ---------------- row softmax (width 4096, fp32 in -> bf16 out) ----------------
__global__ __launch_bounds__(256) void softmax_row4096(const float* __restrict__ in,
                                                       uint16_t* __restrict__ out) {
  const long row = blockIdx.x;
  const float* r = in + row * 4096;
  const int tid = threadIdx.x;
  float v[16];
#pragma unroll
  for (int i = 0; i < 4; ++i) {
    float4 a = *(const float4*)(r + tid * 16 + i * 4);
    v[i * 4 + 0] = a.x; v[i * 4 + 1] = a.y; v[i * 4 + 2] = a.z; v[i * 4 + 3] = a.w;
  }
  float m = v[0];
#pragma unroll
  for (int j = 1; j < 16; ++j) m = fmaxf(m, v[j]);
#pragma unroll
  for (int o = 32; o; o >>= 1) m = fmaxf(m, __shfl_xor(m, o));
  __shared__ float red[8];
  if ((tid & 63) == 0) red[tid >> 6] = m;
  __syncthreads();
  m = fmaxf(fmaxf(red[0], red[1]), fmaxf(red[2], red[3]));
  float s = 0.f;
#pragma unroll
  for (int j = 0; j < 16; ++j) { v[j] = __expf(v[j] - m); s += v[j]; }
#pragma unroll
  for (int o = 32; o; o >>= 1) s += __shfl_xor(s, o);
  if ((tid & 63) == 0) red[4 + (tid >> 6)] = s;
  __syncthreads();
  s = (red[4] + red[5]) + (red[6] + red[7]);
  float inv = 1.f / s;
#pragma unroll
  for (int i = 0; i < 4; ++i) {
    ushort4 u = make_ushort4(f2bf_u(v[i * 4 + 0] * inv), f2bf_u(v[i * 4 + 1] * inv),
                             f2bf_u(v[i * 4 + 2] * inv), f2bf_u(v[i * 4 + 3] * inv));
    *(ushort4*)(out + row * 4096 + tid * 16 + i * 4) = u;
  }
}

// ---------------- bf16 transpose: out[c][r] = in[r][c], 64x64 LDS tiles ----------------
__global__ __launch_bounds__(256) void transpose_bf16(const uint16_t* __restrict__ in,
                                                      uint16_t* __restrict__ out, int R, int C) {
  __shared__ uint16_t t[64][68];
  const int tid = threadIdx.x;
  const int tr = tid >> 4;         // 0..15
  const int tc4 = (tid & 15) * 4;  // 0..60
  const int bx = blockIdx.x;       // col tile
  const int by = blockIdx.y;       // row tile
#pragma unroll
  for (int i = 0; i < 4; ++i) {
    ushort4 v = *(const ushort4*)&in[(long)(by * 64 + tr + i * 16) * C + bx * 64 + tc4];
    *(ushort4*)&t[tr + i * 16][tc4] = v;
  }
  __syncthreads();
#pragma unroll
  for (int i = 0; i < 4; ++i) {
    int oc = tr + i * 16;
    ushort4 v = make_ushort4(t[tc4 + 0][oc], t[tc4 + 1][oc], t[tc4 + 2][oc], t[tc4 + 3][oc]);
    *(ushort4*)&out[(long)(bx * 64 + oc) * R + by * 64 + tc4] = v;
  }
}

// ---------------- host ----------------
extern "C" void kernel_launch(void* const* d_in, const int* in_sizes, int n_in,
                              void* d_out, int out_size, void* d_ws, size_t ws_size,
                              hipStream_t stream) {
  const float* x  = (const float*)d_in[0];
  const float* W1 = (const float*)d_in[1];
  const float* W2 = (const float*)d_in[2];
  const float* W3 = (const float*)d_in[3];
  const float* W4 = (const float*)d_in[4];
  const float* Wo = (const float*)d_in[5];

  char* ws = (char*)d_ws;
  const long SD  = (long)SEQ * DIM;  // 8,388,608
  const long BSD = (long)NB * SD;    // 33,554,432
  const long DD  = (long)DIM * DIM;  // 16,777,216

  // workspace layout (436,207,616 bytes total)
  bf16_t* xbf  = (bf16_t*)(ws + 0L);           // 67.1 MB  x in bf16
  bf16_t* xAT  = (bf16_t*)(ws + 67108864L);    // 67.1 MB  xA^T [b][d][s]; later y_in
  bf16_t* xBT  = (bf16_t*)(ws + 134217728L);   // 67.1 MB  xB^T [b][e][s]; later xO_sm
  bf16_t* xC   = (bf16_t*)(ws + 201326592L);   // 67.1 MB  xC   [b][s][d]
  float*  SQ   = (float*) (ws + 268435456L);   // 67.1 MB  sq raw fp32 (per batch); also xO raw
  bf16_t* sqmT = (bf16_t*)(ws + 335544320L);   // 33.6 MB  softmax(sq)^T bf16 [e][d]
  bf16_t* Wbf  = (bf16_t*)(ws + 369098752L);   // 33.6 MB  current weight in bf16
  bf16_t* T1   = (bf16_t*)(ws + 402653184L);   // 33.6 MB  softmax(sq) bf16 [d][e]
  (void)ws_size; (void)in_sizes; (void)n_in; (void)out_size;

  // x -> bf16
  cvt_f32_bf16_k<<<2048, 256, 0, stream>>>(x, (uint16_t*)xbf, BSD);

  // xA^T[b][d][s] = sum_k W1[d][k] * x[b][s][k]
  cvt_f32_bf16_k<<<2048, 256, 0, stream>>>(W1, (uint16_t*)Wbf, DD);
  for (int b = 0; b < NB; ++b)
    gemm_bt<0><<<(DIM / 128) * (SEQ / 128), 256, 0, stream>>>(
        Wbf, xbf + b * SD, (void*)(xAT + b * SD), nullptr, DIM, SEQ, DIM);

  // xB^T
  cvt_f32_bf16_k<<<2048, 256, 0, stream>>>(W2, (uint16_t*)Wbf, DD);
  for (int b = 0; b < NB; ++b)
    gemm_bt<0><<<(DIM / 128) * (SEQ / 128), 256, 0, stream>>>(
        Wbf, xbf + b * SD, (void*)(xBT + b * SD), nullptr, DIM, SEQ, DIM);

  // xC[b][s][d] = sum_k x[b][s][k] * W3[d][k]   (all batches at once)
  cvt_f32_bf16_k<<<2048, 256, 0, stream>>>(W3, (uint16_t*)Wbf, DD);
  gemm_bt<0><<<(NB * SEQ / 128) * (DIM / 128), 256, 0, stream>>>(
      xbf, Wbf, (void*)xC, nullptr, NB * SEQ, DIM, DIM);

  for (int b = 0; b < NB; ++b) {
    // SQ[d][e] = sum_s xA^T[d][s] * xB^T[e][s]
    gemm_bt<1><<<(DIM / 128) * (DIM / 128), 256, 0, stream>>>(
        xAT + b * SD, xBT + b * SD, (void*)SQ, nullptr, DIM, DIM, SEQ);
    // row softmax over e -> T1 bf16 [d][e]
    softmax_row4096<<<DIM, 256, 0, stream>>>(SQ, (uint16_t*)T1);
    // transpose -> sqmT [e][d]
    transpose_bf16<<<dim3(DIM / 64, DIM / 64), 256, 0, stream>>>(
        (uint16_t*)T1, (uint16_t*)sqmT, DIM, DIM);
    // xO[s][e] = sum_d xC[s][d] * sqmT[e][d]   (fp32 raw into SQ buffer)
    gemm_bt<1><<<(SEQ / 128) * (DIM / 128), 256, 0, stream>>>(
        xC + b * SD, sqmT, (void*)SQ, nullptr, SEQ, DIM, DIM);
    // row softmax over e -> xO_sm bf16 (overwrites xBT[b], no longer needed)
    softmax_row4096<<<SEQ, 256, 0, stream>>>(SQ, (uint16_t*)(xBT + b * SD));
  }

  // y_in = bf16( x + silu(xO_sm @ W4^T) )   -> into xAT buffer
  cvt_f32_bf16_k<<<2048, 256, 0, stream>>>(W4, (uint16_t*)Wbf, DD);
  gemm_bt<2><<<(NB * SEQ / 128) * (DIM / 128), 256, 0, stream>>>(
      xBT, Wbf, (void*)xAT, x, NB * SEQ, DIM, DIM);

  // out = y_in @ Wo^T (fp32)
  cvt_f32_bf16_k<<<2048, 256, 0, stream>>>(Wo, (uint16_t*)Wbf, DD);
  gemm_bt<1><<<(NB * SEQ / 128) * (DIM / 128), 256, 0, stream>>>(
      xAT, Wbf, d_out, nullptr, NB * SEQ, DIM, DIM);
}

// Round 2
// 1932.665 us; speedup vs baseline: 1.3847x; 1.3847x over previous
//
#include <hip/hip_runtime.h>
#include <hip/hip_bf16.h>
#include <stdint.h>

#define DIM 4096
#define NB 4
#define SEQ 2048

typedef __bf16 bf16_t;
typedef __bf16 bf16x8 __attribute__((ext_vector_type(8)));
typedef float f32x4 __attribute__((ext_vector_type(4)));

__device__ __forceinline__ uint16_t f2bf_u(float f) {
  union { float f; uint32_t u; } v; v.f = f;
  uint32_t r = v.u + 0x7FFFu + ((v.u >> 16) & 1u);
  return (uint16_t)(r >> 16);
}

// ---------------- fp32 -> bf16 conversion ----------------
__global__ __launch_bounds__(256) void cvt_f32_bf16_k(const float* __restrict__ in,
                                                      uint16_t* __restrict__ out, long n) {
  long i = ((long)blockIdx.x * 256 + threadIdx.x) * 8;
  long stride = (long)gridDim.x * 256 * 8;
  for (; i < n; i += stride) {
    float4 a = *(const float4*)(in + i);
    float4 b = *(const float4*)(in + i + 4);
    ushort4 o0 = make_ushort4(f2bf_u(a.x), f2bf_u(a.y), f2bf_u(a.z), f2bf_u(a.w));
    ushort4 o1 = make_ushort4(f2bf_u(b.x), f2bf_u(b.y), f2bf_u(b.z), f2bf_u(b.w));
    *(ushort4*)(out + i) = o0;
    *(ushort4*)(out + i + 4) = o1;
  }
}

// ---------------- async global->LDS ----------------
__device__ __forceinline__ void gload16(const void* g, void* l) {
  __builtin_amdgcn_global_load_lds(
      (const __attribute__((address_space(1))) void*)g,
      (__attribute__((address_space(3))) void*)l,
      16, 0, 0);
}

#define BARX() do { asm volatile("" ::: "memory"); __builtin_amdgcn_s_barrier(); asm volatile("" ::: "memory"); } while (0)
#define VMW(n) asm volatile("s_waitcnt vmcnt(" #n ")" ::: "memory")

__device__ __forceinline__ void readA(bf16x8 (&fa)[4][2], const char* p) {
#pragma unroll
  for (int m = 0; m < 4; ++m)
#pragma unroll
    for (int kk = 0; kk < 2; ++kk)
      fa[m][kk] = *(const bf16x8*)(p + m * 2048 + kk * 64);
}
__device__ __forceinline__ void readB(bf16x8 (&fb)[2][2], const char* p) {
#pragma unroll
  for (int n = 0; n < 2; ++n)
#pragma unroll
    for (int kk = 0; kk < 2; ++kk)
      fb[n][kk] = *(const bf16x8*)(p + n * 2048 + kk * 64);
}
__device__ __forceinline__ void mmaQ(f32x4 (&acc)[4][2], const bf16x8 (&fa)[4][2],
                                     const bf16x8 (&fb)[2][2]) {
#pragma unroll
  for (int m = 0; m < 4; ++m)
#pragma unroll
    for (int n = 0; n < 2; ++n)
#pragma unroll
      for (int kk = 0; kk < 2; ++kk)
        acc[m][n] = __builtin_amdgcn_mfma_f32_16x16x32_bf16(fa[m][kk], fb[n][kk], acc[m][n], 0, 0, 0);
}
__device__ __forceinline__ void stageH(const bf16_t* gt, int soff, long rsk, char* lb, int t16) {
  gload16(gt + soff, lb + t16);
  gload16(gt + soff + rsk, lb + 8192 + t16);
}

// ---------------- 256x256 8-phase bf16 GEMM: C[m][n] = sum_k A[m][k]*B[n][k] ----------------
// BM=BN=256, BK=64, 8 waves (2M x 4N, striped), LDS 128KB double-buffered,
// st_16x32 swizzle both-sides, counted vmcnt(6) at phases 4/8, setprio around MFMA.
// EPI 0: bf16 out  1: fp32 out  2: bf16( Xadd + silu(acc) )
template <int EPI>
__global__ __launch_bounds__(512, 2) void gemm256(
    const bf16_t* __restrict__ Abase, const bf16_t* __restrict__ Bbase,
    void* __restrict__ Cout, const float* __restrict__ Xadd,
    int M, int N, int K, long sA, long sB, long sC) {
  __shared__ char smem[131072];
  char* As = smem;            // [2 buf][2 half][128 rows][64 cols] bf16
  char* Bs = smem + 65536;

  const int tid = threadIdx.x;
  const int lane = tid & 63;
  const int wave = tid >> 6;
  const int wm = wave >> 2;   // 0..1  (row stripe)
  const int wn = wave & 3;    // 0..3  (col stripe)
  const int lr = lane & 15;
  const int hi = lane >> 4;

  // bijective XCD swizzle (all our grids are %8==0)
  const int nwg = gridDim.x;
  int wg = blockIdx.x;
  if ((nwg & 7) == 0) wg = (wg & 7) * (nwg >> 3) + (wg >> 3);
  const int nbn = N >> 8;
  const int bm = wg / nbn, bn = wg % nbn;

  const bf16_t* A = Abase + (long)blockIdx.y * sA;
  const bf16_t* B = Bbase + (long)blockIdx.y * sB;
  const bf16_t* A0p = A + (long)(bm * 256) * K;
  const bf16_t* A1p = A0p + (long)128 * K;
  const bf16_t* B0p = B + (long)(bn * 256) * K;
  const bf16_t* B1p = B0p + (long)128 * K;
  const long rsk = (long)64 * K;

  // staging map: LDS linear dest, inverse-swizzled global source (st_16x32)
  const int t16 = tid * 16;
  const int lp = t16 ^ (((t16 >> 9) & 1) << 5);
  const int soff = (lp >> 7) * K + ((lp & 127) >> 1);

  // frag read bases (swizzle XOR is lane-constant: byte bit9 = row bit2 = lr bit2)
  const int swz5 = (lr & 4) << 3;
  const int aB = (((wm * 64 + lr) * 128 + hi * 16) ^ swz5);
  const int bB = (((wn * 32 + lr) * 128 + hi * 16) ^ swz5);

  f32x4 acc[2][2][4][2] = {};
  bf16x8 fa0[4][2], fa1[4][2], fb0[2][2], fb1[2][2];

  // prologue: tile0 -> buf0 (4 halves), tile1 -> buf1 (A0,A1,B0)
  stageH(A0p, soff, rsk, As, t16);
  stageH(A1p, soff, rsk, As + 16384, t16);
  stageH(B0p, soff, rsk, Bs, t16);
  stageH(B1p, soff, rsk, Bs + 16384, t16);
  VMW(4);
  stageH(A0p + 64, soff, rsk, As + 32768, t16);
  stageH(A1p + 64, soff, rsk, As + 49152, t16);
  stageH(B0p + 64, soff, rsk, Bs + 32768, t16);
  VMW(6);
  BARX();

  const int NIT = K >> 7;   // 2 K-tiles (of 64) per iteration
  for (int i = 0; i < NIT; ++i) {
    const bool last = (i == NIT - 1);
    const int k1 = (2 * i + 1) * 64;
    // ph1: Q(mh0,nh0) buf0 ; stage b1.B1 <- tile(2i+1)
    readA(fa0, As + aB);
    readB(fb0, Bs + bB);
    stageH(B1p + k1, soff, rsk, Bs + 49152, t16);
    BARX();
    __builtin_amdgcn_s_setprio(1); mmaQ(acc[0][0], fa0, fb0); __builtin_amdgcn_s_setprio(0);
    BARX();
    // ph2: Q(mh1,nh0) ; stage b0.A0 <- tile(2i+2)
    readA(fa1, As + 16384 + aB);
    if (!last) stageH(A0p + k1 + 64, soff, rsk, As, t16);
    BARX();
    __builtin_amdgcn_s_setprio(1); mmaQ(acc[1][0], fa1, fb0); __builtin_amdgcn_s_setprio(0);
    BARX();
    // ph3: Q(mh0,nh1) ; stage b0.A1
    readB(fb1, Bs + 16384 + bB);
    if (!last) stageH(A1p + k1 + 64, soff, rsk, As + 16384, t16);
    BARX();
    __builtin_amdgcn_s_setprio(1); mmaQ(acc[0][1], fa0, fb1); __builtin_amdgcn_s_setprio(0);
    BARX();
    // ph4: Q(mh1,nh1) ; stage b0.B0 ; counted vmcnt
    if (!last) stageH(B0p + k1 + 64, soff, rsk, Bs, t16);
    BARX();
    __builtin_amdgcn_s_setprio(1); mmaQ(acc[1][1], fa1, fb1); __builtin_amdgcn_s_setprio(0);
    if (last) { VMW(0); } else { VMW(6); }
    BARX();
    // ph5: Q(mh0,nh0) buf1 ; stage b0.B1
    readA(fa0, As + 32768 + aB);
    readB(fb0, Bs + 32768 + bB);
    if (!last) stageH(B1p + k1 + 64, soff, rsk, Bs + 16384, t16);
    BARX();
    __builtin_amdgcn_s_setprio(1); mmaQ(acc[0][0], fa0, fb0); __builtin_amdgcn_s_setprio(0);
    BARX();
    // ph6: Q(mh1,nh0) ; stage b1.A0 <- tile(2i+3)
    readA(fa1, As + 49152 + aB);
    if (!last) stageH(A0p + k1 + 128, soff, rsk, As + 32768, t16);
    BARX();
    __builtin_amdgcn_s_setprio(1); mmaQ(acc[1][0], fa1, fb0); __builtin_amdgcn_s_setprio(0);
    BARX();
    // ph7: Q(mh0,nh1) ; stage b1.A1
    readB(fb1, Bs + 49152 + bB);
    if (!last) stageH(A1p + k1 + 128, soff, rsk, As + 49152, t16);
    BARX();
    __builtin_amdgcn_s_setprio(1); mmaQ(acc[0][1], fa0, fb1); __builtin_amdgcn_s_setprio(0);
    BARX();
    // ph8: Q(mh1,nh1) ; stage b1.B0 ; counted vmcnt
    if (!last) stageH(B0p + k1 + 128, soff, rsk, Bs + 32768, t16);
    BARX();
    __builtin_amdgcn_s_setprio(1); mmaQ(acc[1][1], fa1, fb1); __builtin_amdgcn_s_setprio(0);
    if (!last) VMW(6);
    BARX();
  }

  // epilogue: frag elem j -> row += j, col per D-layout (col=lane&15, row=(lane>>4)*4+j)
  const long cb = (long)blockIdx.y * sC;
#pragma unroll
  for (int mh = 0; mh < 2; ++mh)
#pragma unroll
    for (int nh = 0; nh < 2; ++nh)
#pragma unroll
      for (int m = 0; m < 4; ++m)
#pragma unroll
        for (int n = 0; n < 2; ++n)
#pragma unroll
          for (int j = 0; j < 4; ++j) {
            const int row = bm * 256 + mh * 128 + wm * 64 + m * 16 + hi * 4 + j;
            const int col = bn * 256 + nh * 128 + wn * 32 + n * 16 + lr;
            const long idx = cb + (long)row * N + col;
            const float vv = acc[mh][nh][m][n][j];
            if constexpr (EPI == 0) {
              ((uint16_t*)Cout)[idx] = f2bf_u(vv);
            } else if constexpr (EPI == 1) {
              ((float*)Cout)[idx] = vv;
            } else {
              const float sl = vv / (1.f + __expf(-vv));
              ((uint16_t*)Cout)[idx] = f2bf_u(Xadd[idx] + sl);
            }
          }
}

// ---------------- row softmax (4096 wide, fp32 -> bf16) ----------------
__global__ __launch_bounds__(256) void softmax_row4096(const float* __restrict__ in,
                                                       uint16_t* __restrict__ out) {
  const long row = blockIdx.x;
  const float* r = in + row * 4096;
  const int tid = threadIdx.x;
  float v[16];
#pragma unroll
  for (int i = 0; i < 4; ++i) {
    float4 a = *(const float4*)(r + tid * 16 + i * 4);
    v[i * 4 + 0] = a.x; v[i * 4 + 1] = a.y; v[i * 4 + 2] = a.z; v[i * 4 + 3] = a.w;
  }
  float m = v[0];
#pragma unroll
  for (int j = 1; j < 16; ++j) m = fmaxf(m, v[j]);
#pragma unroll
  for (int o = 32; o; o >>= 1) m = fmaxf(m, __shfl_xor(m, o));
  __shared__ float red[8];
  if ((tid & 63) == 0) red[tid >> 6] = m;
  __syncthreads();
  m = fmaxf(fmaxf(red[0], red[1]), fmaxf(red[2], red[3]));
  float s = 0.f;
#pragma unroll
  for (int j = 0; j < 16; ++j) { v[j] = __expf(v[j] - m); s += v[j]; }
#pragma unroll
  for (int o = 32; o; o >>= 1) s += __shfl_xor(s, o);
  if ((tid & 63) == 0) red[4 + (tid >> 6)] = s;
  __syncthreads();
  s = (red[4] + red[5]) + (red[6] + red[7]);
  float inv = 1.f / s;
#pragma unroll
  for (int i = 0; i < 4; ++i) {
    ushort4 u = make_ushort4(f2bf_u(v[i * 4 + 0] * inv), f2bf_u(v[i * 4 + 1] * inv),
                             f2bf_u(v[i * 4 + 2] * inv), f2bf_u(v[i * 4 + 3] * inv));
    *(ushort4*)(out + row * 4096 + tid * 16 + i * 4) = u;
  }
}

// ---------------- per-row (max, 1/sum(exp)) stats ----------------
__global__ __launch_bounds__(256) void rowstat4096(const float* __restrict__ in,
                                                   float2* __restrict__ stats) {
  const long row = blockIdx.x;
  const float* r = in + row * 4096;
  const int tid = threadIdx.x;
  float v[16];
#pragma unroll
  for (int i = 0; i < 4; ++i) {
    float4 a = *(const float4*)(r + tid * 16 + i * 4);
    v[i * 4 + 0] = a.x; v[i * 4 + 1] = a.y; v[i * 4 + 2] = a.z; v[i * 4 + 3] = a.w;
  }
  float m = v[0];
#pragma unroll
  for (int j = 1; j < 16; ++j) m = fmaxf(m, v[j]);
#pragma unroll
  for (int o = 32; o; o >>= 1) m = fmaxf(m, __shfl_xor(m, o));
  __shared__ float red[8];
  if ((tid & 63) == 0) red[tid >> 6] = m;
  __syncthreads();
  m = fmaxf(fmaxf(red[0], red[1]), fmaxf(red[2], red[3]));
  float s = 0.f;
#pragma unroll
  for (int j = 0; j < 16; ++j) s += __expf(v[j] - m);
#pragma unroll
  for (int o = 32; o; o >>= 1) s += __shfl_xor(s, o);
  if ((tid & 63) == 0) red[4 + (tid >> 6)] = s;
  __syncthreads();
  if (tid == 0) {
    s = (red[4] + red[5]) + (red[6] + red[7]);
    stats[row] = make_float2(m, 1.f / s);
  }
}

// ---------------- fused softmax(exp*inv) + transpose: out[e][d] = sm(in)[d][e] ----------------
__global__ __launch_bounds__(256) void transposeSM(const float* __restrict__ in,
                                                   const float2* __restrict__ stats,
                                                   uint16_t* __restrict__ out) {
  __shared__ uint16_t t[64][68];
  __shared__ float2 st[64];
  const int tid = threadIdx.x;
  const int bx = blockIdx.x, by = blockIdx.y;
  if (tid < 64) st[tid] = stats[by * 64 + tid];
  __syncthreads();
  const int tr = tid >> 4;
  const int tc4 = (tid & 15) * 4;
#pragma unroll
  for (int i = 0; i < 4; ++i) {
    const int r = tr + i * 16;
    const float2 ms = st[r];
    float4 v = *(const float4*)&in[(long)(by * 64 + r) * 4096 + bx * 64 + tc4];
    t[r][tc4 + 0] = f2bf_u(__expf(v.x - ms.x) * ms.y);
    t[r][tc4 + 1] = f2bf_u(__expf(v.y - ms.x) * ms.y);
    t[r][tc4 + 2] = f2bf_u(__expf(v.z - ms.x) * ms.y);
    t[r][tc4 + 3] = f2bf_u(__expf(v.w - ms.x) * ms.y);
  }
  __syncthreads();
#pragma unroll
  for (int i = 0; i < 4; ++i) {
    const int oc = tr + i * 16;
    ushort4 v = make_ushort4(t[tc4 + 0][oc], t[tc4 + 1][oc], t[tc4 + 2][oc], t[tc4 + 3][oc]);
    *(ushort4*)&out[(long)(bx * 64 + oc) * 4096 + by * 64 + tc4] = v;
  }
}

// ---------------- host ----------------
extern "C" void kernel_launch(void* const* d_in, const int* in_sizes, int n_in,
                              void* d_out, int out_size, void* d_ws, size_t ws_size,
                              hipStream_t stream) {
  const float* x  = (const float*)d_in[0];
  const float* W1 = (const float*)d_in[1];
  const float* W2 = (const float*)d_in[2];
  const float* W3 = (const float*)d_in[3];
  const float* W4 = (const float*)d_in[4];
  const float* Wo = (const float*)d_in[5];

  char* ws = (char*)d_ws;
  const long SD  = (long)SEQ * DIM;
  const long BSD = (long)NB * SD;
  const long DD  = (long)DIM * DIM;

  // workspace layout (436,207,616 bytes == round-1 proven footprint)
  bf16_t* xbf  = (bf16_t*)(ws + 0L);           // x bf16; later y_in bf16
  bf16_t* xAT  = (bf16_t*)(ws + 67108864L);    // xA^T [b][d][s]
  bf16_t* xBT  = (bf16_t*)(ws + 134217728L);   // xB^T [b][e][s]; later xO_sm
  void*   R3   = (void*)  (ws + 201326592L);   // SQ fp32 (per batch); later xC bf16
  bf16_t* Wbf  = (bf16_t*)(ws + 268435456L);   // current weight bf16
  bf16_t* sqmT = (bf16_t*)(ws + 301989888L);   // softmax(sq)^T bf16 [4][e][d]
  float2* stats = (float2*)d_out;              // transient per-batch row stats
  float*  xOraw = (float*)d_out;               // xO raw fp32 (full d_out)
  (void)ws_size; (void)in_sizes; (void)n_in; (void)out_size;

  cvt_f32_bf16_k<<<2048, 256, 0, stream>>>(x, (uint16_t*)xbf, BSD);

  // xA^T[b][d][s] = W1 @ x_b^T   (batched, grid.y = 4)
  cvt_f32_bf16_k<<<2048, 256, 0, stream>>>(W1, (uint16_t*)Wbf, DD);
  gemm256<0><<<dim3(128, 4), 512, 0, stream>>>(Wbf, xbf, (void*)xAT, nullptr,
                                               DIM, SEQ, DIM, 0, SD, SD);
  // xB^T
  cvt_f32_bf16_k<<<2048, 256, 0, stream>>>(W2, (uint16_t*)Wbf, DD);
  gemm256<0><<<dim3(128, 4), 512, 0, stream>>>(Wbf, xbf, (void*)xBT, nullptr,
                                               DIM, SEQ, DIM, 0, SD, SD);

  // per batch: SQ = xA^T @ xB, softmax rows, transposed bf16 -> sqmT[b]
  for (int b = 0; b < NB; ++b) {
    gemm256<1><<<dim3(256, 1), 512, 0, stream>>>(xAT + b * SD, xBT + b * SD, R3, nullptr,
                                                 DIM, DIM, SEQ, 0, 0, 0);
    rowstat4096<<<DIM, 256, 0, stream>>>((const float*)R3, stats);
    transposeSM<<<dim3(64, 64), 256, 0, stream>>>((const float*)R3, stats,
                                                  (uint16_t*)(sqmT + b * DD));
  }

  // xC = x @ W3^T  (batch folded into M) -> R3 (SQ scratch dead)
  cvt_f32_bf16_k<<<2048, 256, 0, stream>>>(W3, (uint16_t*)Wbf, DD);
  gemm256<0><<<dim3(512, 1), 512, 0, stream>>>(xbf, Wbf, R3, nullptr,
                                               NB * SEQ, DIM, DIM, 0, 0, 0);

  // xO[b][s][e] = xC_b @ sqmT_b^T  (batched) -> d_out fp32 scratch
  gemm256<1><<<dim3(128, 4), 512, 0, stream>>>((const bf16_t*)R3, sqmT, (void*)xOraw, nullptr,
                                               SEQ, DIM, DIM, SD, DD, SD);
  // softmax rows of xO -> xO_sm bf16 (overwrites xBT)
  softmax_row4096<<<NB * SEQ, 256, 0, stream>>>(xOraw, (uint16_t*)xBT);

  // y_in = bf16( x + silu(xO_sm @ W4^T) ) -> xbf region
  cvt_f32_bf16_k<<<2048, 256, 0, stream>>>(W4, (uint16_t*)Wbf, DD);
  gemm256<2><<<dim3(512, 1), 512, 0, stream>>>(xBT, Wbf, (void*)xbf, x,
                                               NB * SEQ, DIM, DIM, 0, 0, 0);

  // out = y_in @ Wo^T (fp32)
  cvt_f32_bf16_k<<<2048, 256, 0, stream>>>(Wo, (uint16_t*)Wbf, DD);
  gemm256<1><<<dim3(512, 1), 512, 0, stream>>>(xbf, Wbf, d_out, nullptr,
                                               NB * SEQ, DIM, DIM, 0, 0, 0);
}

// Round 3
// 1805.184 us; speedup vs baseline: 1.4825x; 1.0706x over previous
//
#include <hip/hip_runtime.h>
#include <hip/hip_bf16.h>
#include <stdint.h>

#define DIM 4096
#define NB 4
#define SEQ 2048

typedef __bf16 bf16_t;
typedef __bf16 bf16x8 __attribute__((ext_vector_type(8)));
typedef float f32x4 __attribute__((ext_vector_type(4)));

__device__ __forceinline__ uint16_t f2bf_u(float f) {
  union { float f; uint32_t u; } v; v.f = f;
  uint32_t r = v.u + 0x7FFFu + ((v.u >> 16) & 1u);
  return (uint16_t)(r >> 16);
}

// ---------------- fp32 -> bf16 conversion ----------------
__global__ __launch_bounds__(256) void cvt_f32_bf16_k(const float* __restrict__ in,
                                                      uint16_t* __restrict__ out, long n) {
  long i = ((long)blockIdx.x * 256 + threadIdx.x) * 8;
  long stride = (long)gridDim.x * 256 * 8;
  for (; i < n; i += stride) {
    float4 a = *(const float4*)(in + i);
    float4 b = *(const float4*)(in + i + 4);
    ushort4 o0 = make_ushort4(f2bf_u(a.x), f2bf_u(a.y), f2bf_u(a.z), f2bf_u(a.w));
    ushort4 o1 = make_ushort4(f2bf_u(b.x), f2bf_u(b.y), f2bf_u(b.z), f2bf_u(b.w));
    *(ushort4*)(out + i) = o0;
    *(ushort4*)(out + i + 4) = o1;
  }
}

// ---------------- async global->LDS ----------------
__device__ __forceinline__ void gload16(const void* g, void* l) {
  __builtin_amdgcn_global_load_lds(
      (const __attribute__((address_space(1))) void*)g,
      (__attribute__((address_space(3))) void*)l,
      16, 0, 0);
}

#define BARX() do { asm volatile("" ::: "memory"); __builtin_amdgcn_s_barrier(); asm volatile("" ::: "memory"); } while (0)
#define VMW(n) asm volatile("s_waitcnt vmcnt(" #n ")" ::: "memory")

__device__ __forceinline__ void readA(bf16x8 (&fa)[4][2], const char* p, int c0, int c1) {
#pragma unroll
  for (int m = 0; m < 4; ++m) {
    fa[m][0] = *(const bf16x8*)(p + m * 2048 + c0);
    fa[m][1] = *(const bf16x8*)(p + m * 2048 + c1);
  }
}
__device__ __forceinline__ void readB(bf16x8 (&fb)[2][2], const char* p, int c0, int c1) {
#pragma unroll
  for (int n = 0; n < 2; ++n) {
    fb[n][0] = *(const bf16x8*)(p + n * 2048 + c0);
    fb[n][1] = *(const bf16x8*)(p + n * 2048 + c1);
  }
}
__device__ __forceinline__ void mmaQ(f32x4 (&acc)[4][2], const bf16x8 (&fa)[4][2],
                                     const bf16x8 (&fb)[2][2]) {
#pragma unroll
  for (int m = 0; m < 4; ++m)
#pragma unroll
    for (int n = 0; n < 2; ++n)
#pragma unroll
      for (int kk = 0; kk < 2; ++kk)
        acc[m][n] = __builtin_amdgcn_mfma_f32_16x16x32_bf16(fa[m][kk], fb[n][kk], acc[m][n], 0, 0, 0);
}
__device__ __forceinline__ void stageH(const bf16_t* gt, int soff, long rsk, char* lb, int t16) {
  gload16(gt + soff, lb + t16);
  gload16(gt + soff + rsk, lb + 8192 + t16);
}

// ---------------- 256x256 8-phase bf16 GEMM: C[m][n] = sum_k A[m][k]*B[n][k] ----------------
// BM=BN=256, BK=64, 8 waves (2M x 4N), LDS 128KB double-buffered, 3-bit XOR swizzle
// (chunk bits 4-6 ^= row bits 0-2, both-sides), counted vmcnt(6) at ph4/ph8, setprio.
// EPI 0: bf16 out  1: fp32 out  2: bf16( Xadd + silu(acc) )
template <int EPI>
__global__ __launch_bounds__(512, 2) void gemm256(
    const bf16_t* __restrict__ Abase, const bf16_t* __restrict__ Bbase,
    void* __restrict__ Cout, const float* __restrict__ Xadd,
    int M, int N, int K, long sA, long sB, long sC) {
  __shared__ char smem[131072];
  char* As = smem;            // [2 buf][2 half][128 rows][64 cols] bf16
  char* Bs = smem + 65536;

  const int tid = threadIdx.x;
  const int lane = tid & 63;
  const int wave = tid >> 6;
  const int wm = wave >> 2;   // 0..1  (row stripe)
  const int wn = wave & 3;    // 0..3  (col stripe)
  const int lr = lane & 15;
  const int hi = lane >> 4;

  // bijective XCD swizzle (all our grids are %8==0)
  const int nwg = gridDim.x;
  int wg = blockIdx.x;
  if ((nwg & 7) == 0) wg = (wg & 7) * (nwg >> 3) + (wg >> 3);
  const int nbn = N >> 8;
  const int bm = wg / nbn, bn = wg % nbn;

  const bf16_t* A = Abase + (long)blockIdx.y * sA;
  const bf16_t* B = Bbase + (long)blockIdx.y * sB;
  const bf16_t* A0p = A + (long)(bm * 256) * K;
  const bf16_t* A1p = A0p + (long)128 * K;
  const bf16_t* B0p = B + (long)(bn * 256) * K;
  const bf16_t* B1p = B0p + (long)128 * K;
  const long rsk = (long)64 * K;

  // staging: linear LDS dest, inverse-swizzled global source (3-bit XOR involution)
  const int t16 = tid * 16;
  const int lp = t16 ^ (((t16 >> 7) & 7) << 4);
  const int soff = (lp >> 7) * K + ((lp & 127) >> 1);

  // frag read addressing: row base + swizzled column (kk step applied via XOR 64)
  const int swz = (lr & 7) << 4;
  const int c0 = (hi * 16) ^ swz;
  const int c1 = c0 ^ 64;
  const int aR = (wm * 64 + lr) * 128;
  const int bR = (wn * 32 + lr) * 128;

  f32x4 acc[2][2][4][2] = {};
  bf16x8 fa0[4][2], fa1[4][2], fb0[2][2], fb1[2][2];

  // prologue: tile0 -> buf0 (4 halves), tile1 -> buf1 (A0,A1,B0)
  stageH(A0p, soff, rsk, As, t16);
  stageH(A1p, soff, rsk, As + 16384, t16);
  stageH(B0p, soff, rsk, Bs, t16);
  stageH(B1p, soff, rsk, Bs + 16384, t16);
  VMW(4);
  stageH(A0p + 64, soff, rsk, As + 32768, t16);
  stageH(A1p + 64, soff, rsk, As + 49152, t16);
  stageH(B0p + 64, soff, rsk, Bs + 32768, t16);
  VMW(6);
  BARX();

  const int NIT = K >> 7;   // 2 K-tiles (of 64) per iteration
  for (int i = 0; i < NIT; ++i) {
    const bool last = (i == NIT - 1);
    const int k1 = (2 * i + 1) * 64;
    // ph1: Q(mh0,nh0) buf0 ; stage b1.B1 <- tile(2i+1)
    readA(fa0, As + aR, c0, c1);
    readB(fb0, Bs + bR, c0, c1);
    stageH(B1p + k1, soff, rsk, Bs + 49152, t16);
    BARX();
    __builtin_amdgcn_s_setprio(1); mmaQ(acc[0][0], fa0, fb0); __builtin_amdgcn_s_setprio(0);
    BARX();
    // ph2: Q(mh1,nh0) ; stage b0.A0 <- tile(2i+2)
    readA(fa1, As + 16384 + aR, c0, c1);
    if (!last) stageH(A0p + k1 + 64, soff, rsk, As, t16);
    BARX();
    __builtin_amdgcn_s_setprio(1); mmaQ(acc[1][0], fa1, fb0); __builtin_amdgcn_s_setprio(0);
    BARX();
    // ph3: Q(mh0,nh1) ; stage b0.A1
    readB(fb1, Bs + 16384 + bR, c0, c1);
    if (!last) stageH(A1p + k1 + 64, soff, rsk, As + 16384, t16);
    BARX();
    __builtin_amdgcn_s_setprio(1); mmaQ(acc[0][1], fa0, fb1); __builtin_amdgcn_s_setprio(0);
    BARX();
    // ph4: Q(mh1,nh1) ; stage b0.B0 ; counted vmcnt
    if (!last) stageH(B0p + k1 + 64, soff, rsk, Bs, t16);
    BARX();
    __builtin_amdgcn_s_setprio(1); mmaQ(acc[1][1], fa1, fb1); __builtin_amdgcn_s_setprio(0);
    if (last) { VMW(0); } else { VMW(6); }
    BARX();
    // ph5: Q(mh0,nh0) buf1 ; stage b0.B1
    readA(fa0, As + 32768 + aR, c0, c1);
    readB(fb0, Bs + 32768 + bR, c0, c1);
    if (!last) stageH(B1p + k1 + 64, soff, rsk, Bs + 16384, t16);
    BARX();
    __builtin_amdgcn_s_setprio(1); mmaQ(acc[0][0], fa0, fb0); __builtin_amdgcn_s_setprio(0);
    BARX();
    // ph6: Q(mh1,nh0) ; stage b1.A0 <- tile(2i+3)
    readA(fa1, As + 49152 + aR, c0, c1);
    if (!last) stageH(A0p + k1 + 128, soff, rsk, As + 32768, t16);
    BARX();
    __builtin_amdgcn_s_setprio(1); mmaQ(acc[1][0], fa1, fb0); __builtin_amdgcn_s_setprio(0);
    BARX();
    // ph7: Q(mh0,nh1) ; stage b1.A1
    readB(fb1, Bs + 49152 + bR, c0, c1);
    if (!last) stageH(A1p + k1 + 128, soff, rsk, As + 49152, t16);
    BARX();
    __builtin_amdgcn_s_setprio(1); mmaQ(acc[0][1], fa0, fb1); __builtin_amdgcn_s_setprio(0);
    BARX();
    // ph8: Q(mh1,nh1) ; stage b1.B0 ; counted vmcnt
    if (!last) stageH(B0p + k1 + 128, soff, rsk, Bs + 32768, t16);
    BARX();
    __builtin_amdgcn_s_setprio(1); mmaQ(acc[1][1], fa1, fb1); __builtin_amdgcn_s_setprio(0);
    if (!last) VMW(6);
    BARX();
  }

  // epilogue: frag elem j -> row += j (D-layout: col=lane&15, row=(lane>>4)*4+j)
  const long cb = (long)blockIdx.y * sC;
#pragma unroll
  for (int mh = 0; mh < 2; ++mh)
#pragma unroll
    for (int nh = 0; nh < 2; ++nh)
#pragma unroll
      for (int m = 0; m < 4; ++m)
#pragma unroll
        for (int n = 0; n < 2; ++n)
#pragma unroll
          for (int j = 0; j < 4; ++j) {
            const int row = bm * 256 + mh * 128 + wm * 64 + m * 16 + hi * 4 + j;
            const int col = bn * 256 + nh * 128 + wn * 32 + n * 16 + lr;
            const long idx = cb + (long)row * N + col;
            const float vv = acc[mh][nh][m][n][j];
            if constexpr (EPI == 0) {
              ((uint16_t*)Cout)[idx] = f2bf_u(vv);
            } else if constexpr (EPI == 1) {
              ((float*)Cout)[idx] = vv;
            } else {
              const float sl = vv / (1.f + __expf(-vv));
              ((uint16_t*)Cout)[idx] = f2bf_u(Xadd[idx] + sl);
            }
          }
}

// ---------------- row softmax (4096 wide, fp32 -> bf16) ----------------
__global__ __launch_bounds__(256) void softmax_row4096(const float* __restrict__ in,
                                                       uint16_t* __restrict__ out) {
  const long row = blockIdx.x;
  const float* r = in + row * 4096;
  const int tid = threadIdx.x;
  float v[16];
#pragma unroll
  for (int i = 0; i < 4; ++i) {
    float4 a = *(const float4*)(r + tid * 16 + i * 4);
    v[i * 4 + 0] = a.x; v[i * 4 + 1] = a.y; v[i * 4 + 2] = a.z; v[i * 4 + 3] = a.w;
  }
  float m = v[0];
#pragma unroll
  for (int j = 1; j < 16; ++j) m = fmaxf(m, v[j]);
#pragma unroll
  for (int o = 32; o; o >>= 1) m = fmaxf(m, __shfl_xor(m, o));
  __shared__ float red[8];
  if ((tid & 63) == 0) red[tid >> 6] = m;
  __syncthreads();
  m = fmaxf(fmaxf(red[0], red[1]), fmaxf(red[2], red[3]));
  float s = 0.f;
#pragma unroll
  for (int j = 0; j < 16; ++j) { v[j] = __expf(v[j] - m); s += v[j]; }
#pragma unroll
  for (int o = 32; o; o >>= 1) s += __shfl_xor(s, o);
  if ((tid & 63) == 0) red[4 + (tid >> 6)] = s;
  __syncthreads();
  s = (red[4] + red[5]) + (red[6] + red[7]);
  float inv = 1.f / s;
#pragma unroll
  for (int i = 0; i < 4; ++i) {
    ushort4 u = make_ushort4(f2bf_u(v[i * 4 + 0] * inv), f2bf_u(v[i * 4 + 1] * inv),
                             f2bf_u(v[i * 4 + 2] * inv), f2bf_u(v[i * 4 + 3] * inv));
    *(ushort4*)(out + row * 4096 + tid * 16 + i * 4) = u;
  }
}

// ---------------- per-row (max, 1/sum(exp)) stats ----------------
__global__ __launch_bounds__(256) void rowstat4096(const float* __restrict__ in,
                                                   float2* __restrict__ stats) {
  const long row = blockIdx.x;
  const float* r = in + row * 4096;
  const int tid = threadIdx.x;
  float v[16];
#pragma unroll
  for (int i = 0; i < 4; ++i) {
    float4 a = *(const float4*)(r + tid * 16 + i * 4);
    v[i * 4 + 0] = a.x; v[i * 4 + 1] = a.y; v[i * 4 + 2] = a.z; v[i * 4 + 3] = a.w;
  }
  float m = v[0];
#pragma unroll
  for (int j = 1; j < 16; ++j) m = fmaxf(m, v[j]);
#pragma unroll
  for (int o = 32; o; o >>= 1) m = fmaxf(m, __shfl_xor(m, o));
  __shared__ float red[8];
  if ((tid & 63) == 0) red[tid >> 6] = m;
  __syncthreads();
  m = fmaxf(fmaxf(red[0], red[1]), fmaxf(red[2], red[3]));
  float s = 0.f;
#pragma unroll
  for (int j = 0; j < 16; ++j) s += __expf(v[j] - m);
#pragma unroll
  for (int o = 32; o; o >>= 1) s += __shfl_xor(s, o);
  if ((tid & 63) == 0) red[4 + (tid >> 6)] = s;
  __syncthreads();
  if (tid == 0) {
    s = (red[4] + red[5]) + (red[6] + red[7]);
    stats[row] = make_float2(m, 1.f / s);
  }
}

// ---------------- fused softmax + transpose: out[e][d] = sm(in)[d][e] ----------------
__global__ __launch_bounds__(256) void transposeSM(const float* __restrict__ in,
                                                   const float2* __restrict__ stats,
                                                   uint16_t* __restrict__ out) {
  __shared__ uint16_t t[64][68];
  __shared__ float2 st[64];
  const int tid = threadIdx.x;
  const int bx = blockIdx.x, by = blockIdx.y;
  if (tid < 64) st[tid] = stats[by * 64 + tid];
  __syncthreads();
  const int tr = tid >> 4;
  const int tc4 = (tid & 15) * 4;
#pragma unroll
  for (int i = 0; i < 4; ++i) {
    const int r = tr + i * 16;
    const float2 ms = st[r];
    float4 v = *(const float4*)&in[(long)(by * 64 + r) * 4096 + bx * 64 + tc4];
    t[r][tc4 + 0] = f2bf_u(__expf(v.x - ms.x) * ms.y);
    t[r][tc4 + 1] = f2bf_u(__expf(v.y - ms.x) * ms.y);
    t[r][tc4 + 2] = f2bf_u(__expf(v.z - ms.x) * ms.y);
    t[r][tc4 + 3] = f2bf_u(__expf(v.w - ms.x) * ms.y);
  }
  __syncthreads();
#pragma unroll
  for (int i = 0; i < 4; ++i) {
    const int oc = tr + i * 16;
    ushort4 v = make_ushort4(t[tc4 + 0][oc], t[tc4 + 1][oc], t[tc4 + 2][oc], t[tc4 + 3][oc]);
    *(ushort4*)&out[(long)(bx * 64 + oc) * 4096 + by * 64 + tc4] = v;
  }
}

// ---------------- host ----------------
extern "C" void kernel_launch(void* const* d_in, const int* in_sizes, int n_in,
                              void* d_out, int out_size, void* d_ws, size_t ws_size,
                              hipStream_t stream) {
  const float* x  = (const float*)d_in[0];
  const float* W1 = (const float*)d_in[1];
  const float* W2 = (const float*)d_in[2];
  const float* W3 = (const float*)d_in[3];
  const float* W4 = (const float*)d_in[4];
  const float* Wo = (const float*)d_in[5];

  char* ws = (char*)d_ws;
  const long SD  = (long)SEQ * DIM;
  const long BSD = (long)NB * SD;
  const long DD  = (long)DIM * DIM;

  // workspace layout (436,207,616 bytes == round-1 proven footprint)
  bf16_t* xbf  = (bf16_t*)(ws + 0L);           // x bf16; later y_in bf16
  bf16_t* xAT  = (bf16_t*)(ws + 67108864L);    // xA^T [b][d][s]
  bf16_t* xBT  = (bf16_t*)(ws + 134217728L);   // xB^T [b][e][s]; later xO_sm
  void*   R3   = (void*)  (ws + 201326592L);   // SQ fp32 (per batch); later xC bf16
  bf16_t* Wbf  = (bf16_t*)(ws + 268435456L);   // current weight bf16
  bf16_t* sqmT = (bf16_t*)(ws + 301989888L);   // softmax(sq)^T bf16 [4][e][d]
  float2* stats = (float2*)d_out;              // transient per-batch row stats
  float*  xOraw = (float*)d_out;               // xO raw fp32 (full d_out)
  (void)ws_size; (void)in_sizes; (void)n_in; (void)out_size;

  cvt_f32_bf16_k<<<2048, 256, 0, stream>>>(x, (uint16_t*)xbf, BSD);

  // xA^T[b][d][s] = W1 @ x_b^T   (batched, grid.y = 4)
  cvt_f32_bf16_k<<<2048, 256, 0, stream>>>(W1, (uint16_t*)Wbf, DD);
  gemm256<0><<<dim3(128, 4), 512, 0, stream>>>(Wbf, xbf, (void*)xAT, nullptr,
                                               DIM, SEQ, DIM, 0, SD, SD);
  // xB^T
  cvt_f32_bf16_k<<<2048, 256, 0, stream>>>(W2, (uint16_t*)Wbf, DD);
  gemm256<0><<<dim3(128, 4), 512, 0, stream>>>(Wbf, xbf, (void*)xBT, nullptr,
                                               DIM, SEQ, DIM, 0, SD, SD);

  // per batch: SQ = xA^T @ xB, softmax rows, transposed bf16 -> sqmT[b]
  for (int b = 0; b < NB; ++b) {
    gemm256<1><<<dim3(256, 1), 512, 0, stream>>>(xAT + b * SD, xBT + b * SD, R3, nullptr,
                                                 DIM, DIM, SEQ, 0, 0, 0);
    rowstat4096<<<DIM, 256, 0, stream>>>((const float*)R3, stats);
    transposeSM<<<dim3(64, 64), 256, 0, stream>>>((const float*)R3, stats,
                                                  (uint16_t*)(sqmT + b * DD));
  }

  // xC = x @ W3^T  (batch folded into M) -> R3 (SQ scratch dead)
  cvt_f32_bf16_k<<<2048, 256, 0, stream>>>(W3, (uint16_t*)Wbf, DD);
  gemm256<0><<<dim3(512, 1), 512, 0, stream>>>(xbf, Wbf, R3, nullptr,
                                               NB * SEQ, DIM, DIM, 0, 0, 0);

  // xO[b][s][e] = xC_b @ sqmT_b^T  (batched) -> d_out fp32 scratch
  gemm256<1><<<dim3(128, 4), 512, 0, stream>>>((const bf16_t*)R3, sqmT, (void*)xOraw, nullptr,
                                               SEQ, DIM, DIM, SD, DD, SD);
  // softmax rows of xO -> xO_sm bf16 (overwrites xBT)
  softmax_row4096<<<NB * SEQ, 256, 0, stream>>>(xOraw, (uint16_t*)xBT);

  // y_in = bf16( x + silu(xO_sm @ W4^T) ) -> xbf region
  cvt_f32_bf16_k<<<2048, 256, 0, stream>>>(W4, (uint16_t*)Wbf, DD);
  gemm256<2><<<dim3(512, 1), 512, 0, stream>>>(xBT, Wbf, (void*)xbf, x,
                                               NB * SEQ, DIM, DIM, 0, 0, 0);

  // out = y_in @ Wo^T (fp32)
  cvt_f32_bf16_k<<<2048, 256, 0, stream>>>(Wo, (uint16_t*)Wbf, DD);
  gemm256<1><<<dim3(512, 1), 512, 0, stream>>>(xbf, Wbf, d_out, nullptr,
                                               NB * SEQ, DIM, DIM, 0, 0, 0);
}